// Round 6
// baseline (498.220 us; speedup 1.0000x reference)
//
#include <hip/hip_runtime.h>

// ParametrisedPooling: out[t] = sum_k w[n,k] * x_in[idx[n,k], :], n = indices_target[t]
//
// R6: two-phase L3-chunked gather, execution rebuilt after R5's scratch-spill.
//  - traffic plan (VERIFIED by R5 counters: FETCH 292 MB): split x_in (335.6 MB)
//    into two ~168 MB halves; all CUs gather half 0, advisory grid barrier,
//    then half 1. Per-phase working set fits 256 MB L3 -> repeats are L3 hits.
//  - execution plan (NEW): one WAVE (64 lanes x float2) per output row.
//    tgt/idx/weights/deg are wave-uniform -> readfirstlane -> SGPRs, scalar
//    branches. Accumulators: float2 acc[41] = 82 VGPR, statically indexed
//    (all register-array loops fully unrolled, phase loop unroll 1).
//    LB(256,4): VGPR cap 128, 4 blocks/CU -> all 1024 blocks co-resident.
//  - barrier is ADVISORY: no data crosses it (acc in registers). If it ever
//    fails, blocks proceed early: slower, never wrong. Bounded spin.

constexpr int N_SRC  = 655362;
constexpr int N6     = 163830;
constexpr int N7     = 12;
constexpr int N_OUT  = N6 + N7;          // 163842
constexpr int D      = 128;
constexpr int CHUNK  = N_SRC / 2 + 1;    // 327682: halves ~167.8 MB each

constexpr int BLOCK  = 256;
constexpr int GRID   = 1024;             // 4 blocks/CU x 256 CU, co-resident
constexpr int NWAVES = GRID * (BLOCK / 64);               // 4096
constexpr int ROWS   = (N_OUT + NWAVES - 1) / NWAVES;     // 41 contiguous rows/wave

__global__ __launch_bounds__(BLOCK, 4) void pool_kernel(
    const float* __restrict__ x_in,
    const float* __restrict__ w6,
    const float* __restrict__ w7,
    const int*   __restrict__ idx6,
    const int*   __restrict__ idx7,
    const int*   __restrict__ tgt,
    float*       __restrict__ out,
    unsigned int* barrier_cnt)
{
    const int lane = threadIdx.x & 63;
    const int wid  = __builtin_amdgcn_readfirstlane(
                         (blockIdx.x * BLOCK + (int)threadIdx.x) >> 6);
    const int row0 = wid * ROWS;

    float2 acc[ROWS];
#pragma unroll
    for (int r = 0; r < ROWS; ++r) acc[r] = make_float2(0.f, 0.f);

#pragma unroll 1
    for (int phase = 0; phase < 2; ++phase) {
#pragma unroll
        for (int r = 0; r < ROWS; ++r) {
            const int row = row0 + r;
            if (row < N_OUT) {               // wave-uniform (scalar) guard
                const int n = __builtin_amdgcn_readfirstlane(tgt[row]);
                const int*   ip;
                const float* wp;
                int deg;
                if (n < N6) {
                    ip = idx6 + 6 * (size_t)n;  wp = w6 + 6 * (size_t)n;  deg = 6;
                } else {
                    const int m = n - N6;
                    ip = idx7 + 7 * (size_t)m;  wp = w7 + 7 * (size_t)m;  deg = 7;
                }
#pragma unroll
                for (int k = 0; k < 7; ++k) {
                    if (k < deg) {           // scalar branch (deg uniform)
                        const int s = __builtin_amdgcn_readfirstlane(ip[k]);
                        if ((phase == 0) == (s < CHUNK)) {   // scalar branch
                            const float w  = wp[k];
                            const float2 v = *reinterpret_cast<const float2*>(
                                x_in + (size_t)s * D + lane * 2);
                            acc[r].x += w * v.x;
                            acc[r].y += w * v.y;
                        }
                    }
                }
            }
        }
        if (phase == 0 && barrier_cnt != nullptr) {
            // advisory grid barrier: keeps all CUs in the same x_in half
            if (threadIdx.x == 0) {
                __hip_atomic_fetch_add(barrier_cnt, 1u,
                                       __ATOMIC_ACQ_REL, __HIP_MEMORY_SCOPE_AGENT);
                int spins = 0;
                while (__hip_atomic_load(barrier_cnt, __ATOMIC_ACQUIRE,
                                         __HIP_MEMORY_SCOPE_AGENT) < (unsigned)GRID
                       && spins < 4096) {
                    __builtin_amdgcn_s_sleep(4);
                    ++spins;
                }
            }
            __syncthreads();
        }
    }

#pragma unroll
    for (int r = 0; r < ROWS; ++r) {
        const int row = row0 + r;
        if (row < N_OUT) {
            float* op = out + (size_t)row * D + lane * 2;
            __builtin_nontemporal_store(acc[r].x, op + 0);
            __builtin_nontemporal_store(acc[r].y, op + 1);
        }
    }
}

extern "C" void kernel_launch(void* const* d_in, const int* in_sizes, int n_in,
                              void* d_out, int out_size, void* d_ws, size_t ws_size,
                              hipStream_t stream) {
    const float* x_in = (const float*)d_in[0];
    const float* w6   = (const float*)d_in[1];
    const float* w7   = (const float*)d_in[2];
    const int*   idx6 = (const int*)d_in[3];
    const int*   idx7 = (const int*)d_in[4];
    const int*   tgt  = (const int*)d_in[5];
    float*       out  = (float*)d_out;

    unsigned int* barrier_cnt = nullptr;
    if (ws_size >= sizeof(unsigned int)) {
        barrier_cnt = (unsigned int*)d_ws;
        hipMemsetAsync(barrier_cnt, 0, sizeof(unsigned int), stream);
    }

    pool_kernel<<<GRID, BLOCK, 0, stream>>>(x_in, w6, w7, idx6, idx7, tgt,
                                            out, barrier_cnt);
}

// Round 7
// 496.294 us; speedup vs baseline: 1.0039x; 1.0039x over previous
//
#include <hip/hip_runtime.h>

// ParametrisedPooling: out[t] = sum_k w[n,k] * x_in[idx[n,k], :], n = indices_target[t]
//
// R7: two-phase L3-chunked gather (traffic plan twice-verified: FETCH ~290 MB
// vs ~550 MB unphased), execution rebuilt to kill the R5/R6 latency chains:
//  - PROLOGUE: block stages its 168 rows' metadata (idx/w/deg) into LDS via
//    cooperative independent loads -> phase loops have ONE-deep global chains
//    (LDS addr -> gather), 6 independent 512B gathers/row, unrolled -> deep MLP.
//  - BATCHED phases (11+10 rows) with generation-counted advisory barriers:
//    live accs only float4[11] = 44 VGPR -> no spill under LB(256,4).
//  - Barrier is ADVISORY (no data crosses it): bounded spin, failure = slower
//    never wrong. Grid = 1024 blocks, 4/CU co-resident.

constexpr int N_SRC = 655362;
constexpr int N6    = 163830;
constexpr int N7    = 12;
constexpr int N_OUT = N6 + N7;            // 163842
constexpr int D     = 128;
constexpr int CHUNK = N_SRC / 2 + 1;      // 327682: halves ~167.8 MB each

constexpr int BLOCK = 256;
constexpr int GRID  = 1024;               // 4 blocks/CU x 256 CU
constexpr int GPB   = BLOCK / 32;         // 8 groups (32 lanes) per block
constexpr int NG    = GRID * GPB;         // 8192 groups
constexpr int ROWS  = (N_OUT + NG - 1) / NG;   // 21 (row = g + r*NG, guard r=20)
constexpr int B0    = 11;                 // batch 0 rows
constexpr int B1    = ROWS - B0;          // 10

struct Smem {
    int   idx[ROWS][GPB][8];
    float w  [ROWS][GPB][8];
    int   deg[ROWS][GPB];
};

__device__ __forceinline__ void adv_barrier(unsigned int* cnt, unsigned target) {
    __syncthreads();                       // whole block done with prev segment
    if (cnt != nullptr) {
        if (threadIdx.x == 0) {
            __hip_atomic_fetch_add(cnt, 1u, __ATOMIC_ACQ_REL,
                                   __HIP_MEMORY_SCOPE_AGENT);
            int spins = 0;
            while (__hip_atomic_load(cnt, __ATOMIC_ACQUIRE,
                                     __HIP_MEMORY_SCOPE_AGENT) < target
                   && spins < 20000) {
                __builtin_amdgcn_s_sleep(2);
                ++spins;
            }
        }
        __syncthreads();
    }
}

template <int R0, int RN, int PHASE>
__device__ __forceinline__ void seg(float4* __restrict__ acc,
                                    const Smem& sm, int gl, int lane,
                                    const float* __restrict__ x_in) {
#pragma unroll
    for (int r = R0; r < R0 + RN; ++r) {
        const int deg = sm.deg[r][gl];     // broadcast LDS read (0 if inactive)
#pragma unroll
        for (int k = 0; k < 7; ++k) {
            if (k < deg) {
                const int s = sm.idx[r][gl][k];
                if ((PHASE == 0) == (s < CHUNK)) {
                    const float w  = sm.w[r][gl][k];
                    const float4 v = *reinterpret_cast<const float4*>(
                        x_in + (size_t)s * D + lane * 4);
                    acc[r - R0].x += w * v.x;
                    acc[r - R0].y += w * v.y;
                    acc[r - R0].z += w * v.z;
                    acc[r - R0].w += w * v.w;
                }
            }
        }
    }
}

template <int R0, int RN>
__device__ __forceinline__ void store_rows(const float4* __restrict__ acc,
                                           int g, int lane,
                                           float* __restrict__ out) {
#pragma unroll
    for (int r = R0; r < R0 + RN; ++r) {
        const int row = g + r * NG;
        if (row < N_OUT) {
            float* op = out + (size_t)row * D + lane * 4;
            __builtin_nontemporal_store(acc[r - R0].x, op + 0);
            __builtin_nontemporal_store(acc[r - R0].y, op + 1);
            __builtin_nontemporal_store(acc[r - R0].z, op + 2);
            __builtin_nontemporal_store(acc[r - R0].w, op + 3);
        }
    }
}

__global__ __launch_bounds__(BLOCK, 4) void pool_kernel(
    const float* __restrict__ x_in,
    const float* __restrict__ w6,
    const float* __restrict__ w7,
    const int*   __restrict__ idx6,
    const int*   __restrict__ idx7,
    const int*   __restrict__ tgt,
    float*       __restrict__ out,
    unsigned int* barrier_cnt)
{
    __shared__ Smem sm;

    // ---- prologue: resolve metadata for this block's 168 rows into LDS ----
    for (int e = threadIdx.x; e < ROWS * GPB; e += BLOCK) {
        const int r   = e / GPB;
        const int gl  = e % GPB;
        const int row = (blockIdx.x * GPB + gl) + r * NG;
        int deg = 0;
        if (row < N_OUT) {
            const int n = tgt[row];
            if (n < N6) {
                deg = 6;
                const int*   ip = idx6 + 6 * (size_t)n;
                const float* wp = w6   + 6 * (size_t)n;
#pragma unroll
                for (int k = 0; k < 6; ++k) {
                    sm.idx[r][gl][k] = ip[k];
                    sm.w  [r][gl][k] = wp[k];
                }
            } else {
                deg = 7;
                const int m = n - N6;
                const int*   ip = idx7 + 7 * (size_t)m;
                const float* wp = w7   + 7 * (size_t)m;
#pragma unroll
                for (int k = 0; k < 7; ++k) {
                    sm.idx[r][gl][k] = ip[k];
                    sm.w  [r][gl][k] = wp[k];
                }
            }
        }
        sm.deg[r][gl] = deg;
    }
    __syncthreads();

    const int gl   = threadIdx.x >> 5;
    const int lane = threadIdx.x & 31;
    const int g    = blockIdx.x * GPB + gl;

    float4 acc[B0];

    // ---- batch A (rows 0..10) ----
#pragma unroll
    for (int i = 0; i < B0; ++i) acc[i] = make_float4(0.f, 0.f, 0.f, 0.f);
    seg<0, B0, 0>(acc, sm, gl, lane, x_in);          // lower half of x_in
    adv_barrier(barrier_cnt, 1u * GRID);
    seg<0, B0, 1>(acc, sm, gl, lane, x_in);          // upper half
    store_rows<0, B0>(acc, g, lane, out);
    adv_barrier(barrier_cnt, 2u * GRID);

    // ---- batch B (rows 11..20) ----
#pragma unroll
    for (int i = 0; i < B1; ++i) acc[i] = make_float4(0.f, 0.f, 0.f, 0.f);
    seg<B0, B1, 0>(acc, sm, gl, lane, x_in);         // lower half
    adv_barrier(barrier_cnt, 3u * GRID);
    seg<B0, B1, 1>(acc, sm, gl, lane, x_in);         // upper half
    store_rows<B0, B1>(acc, g, lane, out);
}

extern "C" void kernel_launch(void* const* d_in, const int* in_sizes, int n_in,
                              void* d_out, int out_size, void* d_ws, size_t ws_size,
                              hipStream_t stream) {
    const float* x_in = (const float*)d_in[0];
    const float* w6   = (const float*)d_in[1];
    const float* w7   = (const float*)d_in[2];
    const int*   idx6 = (const int*)d_in[3];
    const int*   idx7 = (const int*)d_in[4];
    const int*   tgt  = (const int*)d_in[5];
    float*       out  = (float*)d_out;

    unsigned int* barrier_cnt = nullptr;
    if (ws_size >= sizeof(unsigned int)) {
        barrier_cnt = (unsigned int*)d_ws;
        hipMemsetAsync(barrier_cnt, 0, sizeof(unsigned int), stream);
    }

    pool_kernel<<<GRID, BLOCK, 0, stream>>>(x_in, w6, w7, idx6, idx7, tgt,
                                            out, barrier_cnt);
}